// Round 7
// baseline (573.821 us; speedup 1.0000x reference)
//
#include <hip/hip_runtime.h>

#define D 128
#define NH 8
#define FOUT 16
#define NEG_SLOPE 0.2f
#define SCAN_BS 1024
#define HIST_BLOCKS 1024

typedef __attribute__((ext_vector_type(8))) short bf16x8;
typedef __attribute__((ext_vector_type(4))) float f32x4;

__device__ __forceinline__ unsigned enc_f(float f) {
    unsigned u = __float_as_uint(f);
    return (u & 0x80000000u) ? ~u : (u | 0x80000000u);
}
__device__ __forceinline__ float dec_f(unsigned u) {
    u = (u & 0x80000000u) ? (u & 0x7fffffffu) : ~u;
    return __uint_as_float(u);
}
__device__ __forceinline__ unsigned short f2bf(float x) {  // round-to-nearest-even
    unsigned u = __float_as_uint(x);
    return (unsigned short)((u + 0x7fffu + ((u >> 16) & 1u)) >> 16);
}

// ---- prep: pack W_src and wc (a_trg-folded W_trg) into MFMA B-fragment order (bf16)
// frag(ntl, c): lane l, elem j -> B[k][col], col = ntl*16 + (l&15),
//               k = c*32 + 16*(j>>2) + 4*((l>>4)&3) + (j&3)
__global__ __launch_bounds__(1024) void prep_kernel(
    const float* __restrict__ W_src, const float* __restrict__ W_trg,
    const float* __restrict__ a_trg,
    unsigned short* __restrict__ Wfrag, unsigned short* __restrict__ wcfrag) {
    __shared__ float wcs[NH][D];
    int t = threadIdx.x;
    {   // wc[h][d] = sum_f a_trg[h,f] * W_trg[h*16+f][d]
        int h = t >> 7, d = t & 127;
        float acc = 0.f;
#pragma unroll
        for (int f = 0; f < FOUT; ++f)
            acc += a_trg[h * FOUT + f] * W_trg[(h * FOUT + f) * D + d];
        wcs[h][d] = acc;
    }
    __syncthreads();
    for (int o = t; o < D * D; o += 1024) {
        int j = o & 7, l = (o >> 3) & 63, c = (o >> 9) & 3, ntl = o >> 11;
        int col = ntl * 16 + (l & 15);
        int k = c * 32 + ((j >> 2) << 4) + (((l >> 4) & 3) << 2) + (j & 3);
        Wfrag[o] = f2bf(W_src[col * D + k]);
    }
    for (int o = t; o < 2048; o += 1024) {
        int j = o & 7, l = (o >> 3) & 63, c = o >> 9;
        int h = l & 15;
        int k = c * 32 + ((j >> 2) << 4) + (((l >> 4) & 3) << 2) + (j & 3);
        wcfrag[o] = (h < NH) ? f2bf(wcs[h][k]) : (unsigned short)0;
    }
}

// ---- fused: blocks [0,PB): MFMA projection, 32 nodes/block, no LDS, no barriers
//             blocks [PB,..): target histogram over edges
__global__ __launch_bounds__(256) void projhist_kernel(
    const float* __restrict__ src, const float* __restrict__ trg,
    const unsigned short* __restrict__ Wfrag, const unsigned short* __restrict__ wcfrag,
    const float* __restrict__ a_src, const int* __restrict__ ei,
    unsigned short* __restrict__ projb,
    float* __restrict__ s_src, float* __restrict__ s_trg,
    unsigned* __restrict__ gmax_enc, int* __restrict__ counts,
    int N, int E, int PB) {
    int tid = threadIdx.x;

    if (blockIdx.x >= PB) {   // -------- histogram part
        for (int e = (blockIdx.x - PB) * 256 + tid; e < E; e += HIST_BLOCKS * 256)
            atomicAdd(counts + ei[E + e], 1);
        return;
    }

    // -------- projection: wave w -> 16 nodes (mt) x 64 features (nh half)
    int lane = tid & 63;
    int w = tid >> 6;
    int mt = w >> 1, nh = w & 1;
    int nh4 = nh * 4;
    int cl = lane & 15, rq = lane >> 4;
    int n0 = blockIdx.x * 32;
    int anode = n0 + mt * 16 + cl;   // A-row this lane supplies

    // W fragments (L2-hot, coalesced)
    const bf16x8* WF = (const bf16x8*)Wfrag;
    const bf16x8* WCF = (const bf16x8*)wcfrag;
    bf16x8 wf[4][4];
#pragma unroll
    for (int nt = 0; nt < 4; ++nt)
#pragma unroll
        for (int c = 0; c < 4; ++c)
            wf[nt][c] = WF[((nh4 + nt) * 4 + c) * 64 + lane];
    bf16x8 wcf[4];
#pragma unroll
    for (int c = 0; c < 4; ++c) wcf[c] = WCF[c * 64 + lane];

    f32x4 acc[4] = {{0.f, 0.f, 0.f, 0.f}, {0.f, 0.f, 0.f, 0.f},
                    {0.f, 0.f, 0.f, 0.f}, {0.f, 0.f, 0.f, 0.f}};
    f32x4 acc2 = {0.f, 0.f, 0.f, 0.f};

#pragma unroll
    for (int c = 0; c < 4; ++c) {
        size_t off = (size_t)anode * D + c * 32 + (rq << 2);
        float4 a0 = *(const float4*)(src + off);
        float4 a1 = *(const float4*)(src + off + 16);
        bf16x8 af;
        af[0] = (short)f2bf(a0.x); af[1] = (short)f2bf(a0.y);
        af[2] = (short)f2bf(a0.z); af[3] = (short)f2bf(a0.w);
        af[4] = (short)f2bf(a1.x); af[5] = (short)f2bf(a1.y);
        af[6] = (short)f2bf(a1.z); af[7] = (short)f2bf(a1.w);
#pragma unroll
        for (int nt = 0; nt < 4; ++nt)
            acc[nt] = __builtin_amdgcn_mfma_f32_16x16x32_bf16(af, wf[nt][c], acc[nt], 0, 0, 0);

        float4 t0 = *(const float4*)(trg + off);
        float4 t1 = *(const float4*)(trg + off + 16);
        bf16x8 tf;
        tf[0] = (short)f2bf(t0.x); tf[1] = (short)f2bf(t0.y);
        tf[2] = (short)f2bf(t0.z); tf[3] = (short)f2bf(t0.w);
        tf[4] = (short)f2bf(t1.x); tf[5] = (short)f2bf(t1.y);
        tf[6] = (short)f2bf(t1.z); tf[7] = (short)f2bf(t1.w);
        acc2 = __builtin_amdgcn_mfma_f32_16x16x32_bf16(tf, wcf[c], acc2, 0, 0, 0);
    }

    // epilogue: projb (bf16), s_src (a_src-folded), s_trg, maxes
    int nb0 = n0 + mt * 16;
    float lmax = -1e30f;
#pragma unroll
    for (int nt = 0; nt < 4; ++nt) {
        int head = nh4 + nt;
        float av = a_src[head * FOUT + cl];
#pragma unroll
        for (int i = 0; i < 4; ++i) {
            int node = nb0 + rq * 4 + i;
            projb[(size_t)node * D + head * 16 + cl] = f2bf(acc[nt][i]);
            float p = acc[nt][i] * av;
            p += __shfl_xor(p, 1); p += __shfl_xor(p, 2);
            p += __shfl_xor(p, 4); p += __shfl_xor(p, 8);
            if (cl == 0) s_src[(size_t)node * NH + head] = p;
            lmax = fmaxf(lmax, p);
        }
    }
    float tmax = -1e30f;
#pragma unroll
    for (int i = 0; i < 4; ++i) {
        int node = nb0 + rq * 4 + i;
        if (cl < NH) {
            float dv = acc2[i];
            s_trg[(size_t)node * NH + cl] = dv;
            tmax = fmaxf(tmax, dv);
        }
    }
#pragma unroll
    for (int off = 1; off < 64; off <<= 1) {
        lmax = fmaxf(lmax, __shfl_xor(lmax, off));
        tmax = fmaxf(tmax, __shfl_xor(tmax, off));
    }
    if (lane == 0) {
        atomicMax(gmax_enc + 0, enc_f(lmax));
        atomicMax(gmax_enc + 1, enc_f(tmax));
    }
}

// ---- scans (cursor = exclusive offsets); scan2 also finalizes the global max
__global__ void scan1_kernel(const int* __restrict__ counts, int* __restrict__ cursor,
                             int* __restrict__ bsum, int N) {
    __shared__ int tmp[SCAN_BS];
    int t = threadIdx.x, g = blockIdx.x * SCAN_BS + t;
    int v = (g < N) ? counts[g] : 0;
    tmp[t] = v;
    __syncthreads();
    for (int off = 1; off < SCAN_BS; off <<= 1) {
        int x = (t >= off) ? tmp[t - off] : 0;
        __syncthreads();
        tmp[t] += x;
        __syncthreads();
    }
    if (g < N) cursor[g] = tmp[t] - v;
    if (t == SCAN_BS - 1) bsum[blockIdx.x] = tmp[t];
}
__global__ void scan2_kernel(int* __restrict__ bsum, int nb,
                             const unsigned* __restrict__ ge, float* __restrict__ gmaxf) {
    __shared__ int tmp[128];
    int t = threadIdx.x;
    int v = (t < nb) ? bsum[t] : 0;
    tmp[t] = v;
    __syncthreads();
    for (int off = 1; off < 128; off <<= 1) {
        int x = (t >= off) ? tmp[t - off] : 0;
        __syncthreads();
        tmp[t] += x;
        __syncthreads();
    }
    if (t < nb) bsum[t] = tmp[t] - v;
    if (t == 0) gmaxf[0] = dec_f(ge[0]) + dec_f(ge[1]);  // M >= true max; cancels
}
__global__ void scan3_kernel(int* __restrict__ cursor, const int* __restrict__ bsum, int N) {
    int g = blockIdx.x * SCAN_BS + threadIdx.x;
    if (g < N) cursor[g] += bsum[blockIdx.x];
}

// ---- scatter edges into CSR buckets (2 edges/thread, int2 reads)
__global__ void scatter_kernel(const int* __restrict__ ei, int* __restrict__ cursor,
                               int* __restrict__ perm_src, int E) {
    int e = 2 * (blockIdx.x * blockDim.x + threadIdx.x);
    if (e + 1 < E) {
        int2 s2 = *((const int2*)(ei + e));
        int2 t2 = *((const int2*)(ei + E + e));
        perm_src[atomicAdd(cursor + t2.x, 1)] = s2.x;
        perm_src[atomicAdd(cursor + t2.y, 1)] = s2.y;
    } else if (e < E) {
        int si = ei[e], ti = ei[E + e];
        perm_src[atomicAdd(cursor + ti, 1)] = si;
    }
}

// ---- per-target aggregation: wave per target (4/block), bf16 gather, no barriers
__global__ __launch_bounds__(256) void agg_kernel(
    const int* __restrict__ cursor_end, const int* __restrict__ counts,
    const int* __restrict__ perm_src,
    const float* __restrict__ s_src, const float* __restrict__ s_trg,
    const unsigned short* __restrict__ projb, const float* __restrict__ gmaxf,
    float* __restrict__ out, int N) {
    int w = threadIdx.x >> 6;
    int lane = threadIdx.x & 63;     // owns features 2*lane, 2*lane+1
    int n = blockIdx.x * 4 + w;
    if (n >= N) return;
    int h = lane >> 3;
    int cnt = counts[n];
    int start = cursor_end[n] - cnt;
    float M = gmaxf[0];
    __shared__ float stg_sh[4][NH];
    __shared__ int sie[4][64];
    __shared__ float wls[4][64][NH + 1];
    if (lane < NH) stg_sh[w][lane] = s_trg[(size_t)n * NH + lane];

    const unsigned* p2 = (const unsigned*)projb;   // bf16x2, row stride 64
    float acc0 = 0.f, acc1 = 0.f, wsum = 0.f;

    for (int base = 0; base < cnt; base += 64) {
        int idx = base + lane;
        if (idx < cnt) {
            int si = perm_src[start + idx];
            sie[w][lane] = si;
            const float* ps = s_src + (size_t)si * NH;
#pragma unroll
            for (int hh = 0; hh < NH; ++hh) {
                float sc = ps[hh] + stg_sh[w][hh];
                sc = sc > 0.f ? sc : NEG_SLOPE * sc;
                wls[w][lane][hh] = __expf(sc - M);
            }
        }
        int m = min(64, cnt - base);
#pragma unroll 4
        for (int j = 0; j < m; ++j) {
            int si = sie[w][j];
            float wgt = wls[w][j][h];
            unsigned pv = p2[(size_t)si * 64 + lane];
            float lo = __uint_as_float(pv << 16);
            float hi = __uint_as_float(pv & 0xffff0000u);
            wsum += wgt;
            acc0 += wgt * lo;
            acc1 += wgt * hi;
        }
    }
    float inv = 1.f / (wsum + 1e-16f);
    *((float2*)(out + (size_t)n * D + 2 * lane)) = make_float2(acc0 * inv, acc1 * inv);
}

extern "C" void kernel_launch(void* const* d_in, const int* in_sizes, int n_in,
                              void* d_out, int out_size, void* d_ws, size_t ws_size,
                              hipStream_t stream) {
    const float* trg   = (const float*)d_in[0];
    const float* src   = (const float*)d_in[1];
    const int*   ei    = (const int*)d_in[2];
    const float* W_trg = (const float*)d_in[3];
    const float* W_src = (const float*)d_in[4];
    const float* a_src = (const float*)d_in[5];
    const float* a_trg = (const float*)d_in[6];
    float* out = (float*)d_out;

    const int N = in_sizes[0] / D;   // 100000
    const int E = in_sizes[2] / 2;   // 1600000

    unsigned short* Wfrag  = (unsigned short*)d_ws;       // 16384 (32 KB)
    unsigned short* wcfrag = Wfrag + D * D;               // 2048  (4 KB)
    unsigned* gmaxe = (unsigned*)(wcfrag + 2048);         // 2 (pad 4)
    float* gmaxf    = (float*)(gmaxe + 4);                // 1 (pad 4)
    float* s_src    = gmaxf + 4;                          // N*8
    float* s_trg    = s_src + (size_t)N * NH;             // N*8
    int*   counts   = (int*)(s_trg + (size_t)N * NH);     // N
    int*   cursor   = counts + N;                         // N
    int*   bsum     = cursor + N;                         // 128
    int*   perm_src = bsum + 128;                         // E
    unsigned short* projb = (unsigned short*)(perm_src + E);  // N*128 bf16

    const int NB = (N + SCAN_BS - 1) / SCAN_BS;    // 98
    const int PB = N / 32;                         // 3125

    hipMemsetAsync(counts, 0, (size_t)N * sizeof(int), stream);
    hipMemsetAsync(gmaxe, 0, 4 * sizeof(unsigned), stream);

    prep_kernel<<<1, 1024, 0, stream>>>(W_src, W_trg, a_trg, Wfrag, wcfrag);
    projhist_kernel<<<PB + HIST_BLOCKS, 256, 0, stream>>>(
        src, trg, Wfrag, wcfrag, a_src, ei, projb, s_src, s_trg, gmaxe, counts, N, E, PB);
    scan1_kernel<<<NB, SCAN_BS, 0, stream>>>(counts, cursor, bsum, N);
    scan2_kernel<<<1, 128, 0, stream>>>(bsum, NB, gmaxe, gmaxf);
    scan3_kernel<<<NB, SCAN_BS, 0, stream>>>(cursor, bsum, N);
    scatter_kernel<<<(E / 2 + 255) / 256, 256, 0, stream>>>(ei, cursor, perm_src, E);
    agg_kernel<<<(N + 3) / 4, 256, 0, stream>>>(cursor, counts, perm_src,
                                                s_src, s_trg, projb, gmaxf, out, N);
}

// Round 8
// 453.505 us; speedup vs baseline: 1.2653x; 1.2653x over previous
//
#include <hip/hip_runtime.h>

#define D 128
#define NH 8
#define FOUT 16
#define NEG_SLOPE 0.2f
#define SCAN_BS 1024
#define HIST_BLOCKS 1024

typedef __attribute__((ext_vector_type(8))) short bf16x8;
typedef __attribute__((ext_vector_type(4))) float f32x4;

__device__ __forceinline__ unsigned enc_f(float f) {
    unsigned u = __float_as_uint(f);
    return (u & 0x80000000u) ? ~u : (u | 0x80000000u);
}
__device__ __forceinline__ float dec_f(unsigned u) {
    u = (u & 0x80000000u) ? (u & 0x7fffffffu) : ~u;
    return __uint_as_float(u);
}
__device__ __forceinline__ unsigned short f2bf(float x) {  // round-to-nearest-even
    unsigned u = __float_as_uint(x);
    return (unsigned short)((u + 0x7fffu + ((u >> 16) & 1u)) >> 16);
}

// ---- prep: pack W_src and wc (a_trg-folded W_trg) into MFMA B-fragment order (bf16)
// frag(ntl, c): lane l, elem j -> B[k][col], col = ntl*16 + (l&15),
//               k = c*32 + 16*(j>>2) + 4*((l>>4)&3) + (j&3)
__global__ __launch_bounds__(1024) void prep_kernel(
    const float* __restrict__ W_src, const float* __restrict__ W_trg,
    const float* __restrict__ a_trg,
    unsigned short* __restrict__ Wfrag, unsigned short* __restrict__ wcfrag) {
    __shared__ float wcs[NH][D];
    int t = threadIdx.x;
    {   // wc[h][d] = sum_f a_trg[h,f] * W_trg[h*16+f][d]
        int h = t >> 7, d = t & 127;
        float acc = 0.f;
#pragma unroll
        for (int f = 0; f < FOUT; ++f)
            acc += a_trg[h * FOUT + f] * W_trg[(h * FOUT + f) * D + d];
        wcs[h][d] = acc;
    }
    __syncthreads();
    for (int o = t; o < D * D; o += 1024) {
        int j = o & 7, l = (o >> 3) & 63, c = (o >> 9) & 3, ntl = o >> 11;
        int col = ntl * 16 + (l & 15);
        int k = c * 32 + ((j >> 2) << 4) + (((l >> 4) & 3) << 2) + (j & 3);
        Wfrag[o] = f2bf(W_src[col * D + k]);
    }
    for (int o = t; o < 2048; o += 1024) {
        int j = o & 7, l = (o >> 3) & 63, c = o >> 9;
        int h = l & 15;
        int k = c * 32 + ((j >> 2) << 4) + (((l >> 4) & 3) << 2) + (j & 3);
        wcfrag[o] = (h < NH) ? f2bf(wcs[h][k]) : (unsigned short)0;
    }
}

// ---- fused: blocks [0,PB): MFMA projection, 64 nodes/block, LDS-staged A
//             blocks [PB,..): target histogram over edges
__global__ __launch_bounds__(256) void projhist_kernel(
    const float* __restrict__ src, const float* __restrict__ trg,
    const unsigned short* __restrict__ Wfrag, const unsigned short* __restrict__ wcfrag,
    const float* __restrict__ a_src, const int* __restrict__ ei,
    unsigned short* __restrict__ projb,
    float* __restrict__ s_src, float* __restrict__ s_trg,
    unsigned* __restrict__ gmax_enc, int* __restrict__ counts,
    int N, int E, int PB) {
    int tid = threadIdx.x;

    if (blockIdx.x >= PB) {   // -------- histogram part
        for (int e = (blockIdx.x - PB) * 256 + tid; e < E; e += HIST_BLOCKS * 256)
            atomicAdd(counts + ei[E + e], 1);
        return;
    }

    // -------- projection: 64 nodes/block; wave w -> rows w*16..w*16+15, all 128 cols
    int lane = tid & 63;
    int w = tid >> 6;
    int cl = lane & 15, rq = lane >> 4;
    int n0 = blockIdx.x * 64;
    int nodes = min(64, N - n0);
    int nwords = nodes * 32;
    int nb0 = n0 + w * 16;

    __shared__ unsigned short tile[64][132];   // bf16, padded row (264 B)

    const bf16x8* WF = (const bf16x8*)Wfrag;
    const bf16x8* WCF = (const bf16x8*)wcfrag;

    // ---- phase 1: stage trg (fp32 -> bf16, coalesced float4 reads)
    {
        const float4* b4 = (const float4*)(trg + (size_t)n0 * D);
        for (int i = tid; i < 2048; i += 256) {
            int r = i >> 5, c = i & 31;
            float4 v = (i < nwords) ? b4[i] : make_float4(0.f, 0.f, 0.f, 0.f);
            ushort4 u;
            u.x = f2bf(v.x); u.y = f2bf(v.y); u.z = f2bf(v.z); u.w = f2bf(v.w);
            *(ushort4*)&tile[r][c * 4] = u;
        }
    }
    __syncthreads();

    f32x4 acc2 = {0.f, 0.f, 0.f, 0.f};
#pragma unroll
    for (int c = 0; c < 4; ++c) {
        const unsigned short* tp = &tile[w * 16 + cl][c * 32 + rq * 4];
        union { unsigned long long q[2]; bf16x8 v; } af;
        af.q[0] = *(const unsigned long long*)tp;
        af.q[1] = *(const unsigned long long*)(tp + 16);
        acc2 = __builtin_amdgcn_mfma_f32_16x16x32_bf16(af.v, WCF[c * 64 + lane], acc2, 0, 0, 0);
    }
    __syncthreads();   // all ds_reads done before restage

    // ---- phase 2: stage src, main GEMM
    {
        const float4* b4 = (const float4*)(src + (size_t)n0 * D);
        for (int i = tid; i < 2048; i += 256) {
            int r = i >> 5, c = i & 31;
            float4 v = (i < nwords) ? b4[i] : make_float4(0.f, 0.f, 0.f, 0.f);
            ushort4 u;
            u.x = f2bf(v.x); u.y = f2bf(v.y); u.z = f2bf(v.z); u.w = f2bf(v.w);
            *(ushort4*)&tile[r][c * 4] = u;
        }
    }
    __syncthreads();

    union { unsigned long long q[2]; bf16x8 v; } af0, af1, af2, af3;
    {
        const unsigned short* tp = &tile[w * 16 + cl][rq * 4];
        af0.q[0] = *(const unsigned long long*)tp;
        af0.q[1] = *(const unsigned long long*)(tp + 16);
        af1.q[0] = *(const unsigned long long*)(tp + 32);
        af1.q[1] = *(const unsigned long long*)(tp + 48);
        af2.q[0] = *(const unsigned long long*)(tp + 64);
        af2.q[1] = *(const unsigned long long*)(tp + 80);
        af3.q[0] = *(const unsigned long long*)(tp + 96);
        af3.q[1] = *(const unsigned long long*)(tp + 112);
    }
    f32x4 acc[8] = {{0.f,0.f,0.f,0.f},{0.f,0.f,0.f,0.f},{0.f,0.f,0.f,0.f},{0.f,0.f,0.f,0.f},
                    {0.f,0.f,0.f,0.f},{0.f,0.f,0.f,0.f},{0.f,0.f,0.f,0.f},{0.f,0.f,0.f,0.f}};
#pragma unroll
    for (int nt = 0; nt < 8; ++nt) {
        acc[nt] = __builtin_amdgcn_mfma_f32_16x16x32_bf16(af0.v, WF[(nt * 4 + 0) * 64 + lane], acc[nt], 0, 0, 0);
        acc[nt] = __builtin_amdgcn_mfma_f32_16x16x32_bf16(af1.v, WF[(nt * 4 + 1) * 64 + lane], acc[nt], 0, 0, 0);
        acc[nt] = __builtin_amdgcn_mfma_f32_16x16x32_bf16(af2.v, WF[(nt * 4 + 2) * 64 + lane], acc[nt], 0, 0, 0);
        acc[nt] = __builtin_amdgcn_mfma_f32_16x16x32_bf16(af3.v, WF[(nt * 4 + 3) * 64 + lane], acc[nt], 0, 0, 0);
    }

    // ---- epilogues
    float lmax = -1e30f, tmax = -1e30f;
#pragma unroll
    for (int i = 0; i < 4; ++i) {
        int node = nb0 + rq * 4 + i;
        if (cl < NH) {
            float dv = acc2[i];
            if (node < N) {
                s_trg[(size_t)node * NH + cl] = dv;
                tmax = fmaxf(tmax, dv);
            }
        }
    }
#pragma unroll
    for (int nt = 0; nt < 8; ++nt) {
        float av = a_src[nt * FOUT + cl];
#pragma unroll
        for (int i = 0; i < 4; ++i) {
            int node = nb0 + rq * 4 + i;
            float p = acc[nt][i] * av;
            p += __shfl_xor(p, 1); p += __shfl_xor(p, 2);
            p += __shfl_xor(p, 4); p += __shfl_xor(p, 8);
            if (node < N) {
                projb[(size_t)node * D + nt * 16 + cl] = f2bf(acc[nt][i]);
                if (cl == 0) s_src[(size_t)node * NH + nt] = p;
                lmax = fmaxf(lmax, p);
            }
        }
    }
#pragma unroll
    for (int off = 1; off < 64; off <<= 1) {
        lmax = fmaxf(lmax, __shfl_xor(lmax, off));
        tmax = fmaxf(tmax, __shfl_xor(tmax, off));
    }
    if (lane == 0) {
        atomicMax(gmax_enc + 0, enc_f(lmax));
        atomicMax(gmax_enc + 1, enc_f(tmax));
    }
}

// ---- scans (cursor = exclusive offsets); scan2 also finalizes the global max
__global__ void scan1_kernel(const int* __restrict__ counts, int* __restrict__ cursor,
                             int* __restrict__ bsum, int N) {
    __shared__ int tmp[SCAN_BS];
    int t = threadIdx.x, g = blockIdx.x * SCAN_BS + t;
    int v = (g < N) ? counts[g] : 0;
    tmp[t] = v;
    __syncthreads();
    for (int off = 1; off < SCAN_BS; off <<= 1) {
        int x = (t >= off) ? tmp[t - off] : 0;
        __syncthreads();
        tmp[t] += x;
        __syncthreads();
    }
    if (g < N) cursor[g] = tmp[t] - v;
    if (t == SCAN_BS - 1) bsum[blockIdx.x] = tmp[t];
}
__global__ void scan2_kernel(int* __restrict__ bsum, int nb,
                             const unsigned* __restrict__ ge, float* __restrict__ gmaxf) {
    __shared__ int tmp[128];
    int t = threadIdx.x;
    int v = (t < nb) ? bsum[t] : 0;
    tmp[t] = v;
    __syncthreads();
    for (int off = 1; off < 128; off <<= 1) {
        int x = (t >= off) ? tmp[t - off] : 0;
        __syncthreads();
        tmp[t] += x;
        __syncthreads();
    }
    if (t < nb) bsum[t] = tmp[t] - v;
    if (t == 0) gmaxf[0] = dec_f(ge[0]) + dec_f(ge[1]);  // M >= true max; cancels
}
__global__ void scan3_kernel(int* __restrict__ cursor, const int* __restrict__ bsum, int N) {
    int g = blockIdx.x * SCAN_BS + threadIdx.x;
    if (g < N) cursor[g] += bsum[blockIdx.x];
}

// ---- scatter edges into CSR buckets (2 edges/thread, int2 reads)
__global__ void scatter_kernel(const int* __restrict__ ei, int* __restrict__ cursor,
                               int* __restrict__ perm_src, int E) {
    int e = 2 * (blockIdx.x * blockDim.x + threadIdx.x);
    if (e + 1 < E) {
        int2 s2 = *((const int2*)(ei + e));
        int2 t2 = *((const int2*)(ei + E + e));
        perm_src[atomicAdd(cursor + t2.x, 1)] = s2.x;
        perm_src[atomicAdd(cursor + t2.y, 1)] = s2.y;
    } else if (e < E) {
        int si = ei[e], ti = ei[E + e];
        perm_src[atomicAdd(cursor + ti, 1)] = si;
    }
}

// ---- per-target aggregation: wave per target (4/block), bf16 gather, no barriers
__global__ __launch_bounds__(256) void agg_kernel(
    const int* __restrict__ cursor_end, const int* __restrict__ counts,
    const int* __restrict__ perm_src,
    const float* __restrict__ s_src, const float* __restrict__ s_trg,
    const unsigned short* __restrict__ projb, const float* __restrict__ gmaxf,
    float* __restrict__ out, int N) {
    int w = threadIdx.x >> 6;
    int lane = threadIdx.x & 63;     // owns features 2*lane, 2*lane+1
    int n = blockIdx.x * 4 + w;
    if (n >= N) return;
    int h = lane >> 3;
    int cnt = counts[n];
    int start = cursor_end[n] - cnt;
    float M = gmaxf[0];
    __shared__ float stg_sh[4][NH];
    __shared__ int sie[4][64];
    __shared__ float wls[4][64][NH + 1];
    if (lane < NH) stg_sh[w][lane] = s_trg[(size_t)n * NH + lane];

    const unsigned* p2 = (const unsigned*)projb;   // bf16x2, row stride 64
    float acc0 = 0.f, acc1 = 0.f, wsum = 0.f;

    for (int base = 0; base < cnt; base += 64) {
        int idx = base + lane;
        if (idx < cnt) {
            int si = perm_src[start + idx];
            sie[w][lane] = si;
            const float* ps = s_src + (size_t)si * NH;
#pragma unroll
            for (int hh = 0; hh < NH; ++hh) {
                float sc = ps[hh] + stg_sh[w][hh];
                sc = sc > 0.f ? sc : NEG_SLOPE * sc;
                wls[w][lane][hh] = __expf(sc - M);
            }
        }
        int m = min(64, cnt - base);
#pragma unroll 4
        for (int j = 0; j < m; ++j) {
            int si = sie[w][j];
            float wgt = wls[w][j][h];
            unsigned pv = p2[(size_t)si * 64 + lane];
            float lo = __uint_as_float(pv << 16);
            float hi = __uint_as_float(pv & 0xffff0000u);
            wsum += wgt;
            acc0 += wgt * lo;
            acc1 += wgt * hi;
        }
    }
    float inv = 1.f / (wsum + 1e-16f);
    *((float2*)(out + (size_t)n * D + 2 * lane)) = make_float2(acc0 * inv, acc1 * inv);
}

extern "C" void kernel_launch(void* const* d_in, const int* in_sizes, int n_in,
                              void* d_out, int out_size, void* d_ws, size_t ws_size,
                              hipStream_t stream) {
    const float* trg   = (const float*)d_in[0];
    const float* src   = (const float*)d_in[1];
    const int*   ei    = (const int*)d_in[2];
    const float* W_trg = (const float*)d_in[3];
    const float* W_src = (const float*)d_in[4];
    const float* a_src = (const float*)d_in[5];
    const float* a_trg = (const float*)d_in[6];
    float* out = (float*)d_out;

    const int N = in_sizes[0] / D;   // 100000
    const int E = in_sizes[2] / 2;   // 1600000

    unsigned short* Wfrag  = (unsigned short*)d_ws;       // 16384 (32 KB)
    unsigned short* wcfrag = Wfrag + D * D;               // 2048  (4 KB)
    unsigned* gmaxe = (unsigned*)(wcfrag + 2048);         // 2 (pad 4)
    float* gmaxf    = (float*)(gmaxe + 4);                // 1 (pad 4)
    float* s_src    = gmaxf + 4;                          // N*8
    float* s_trg    = s_src + (size_t)N * NH;             // N*8
    int*   counts   = (int*)(s_trg + (size_t)N * NH);     // N
    int*   cursor   = counts + N;                         // N
    int*   bsum     = cursor + N;                         // 128
    int*   perm_src = bsum + 128;                         // E
    unsigned short* projb = (unsigned short*)(perm_src + E);  // N*128 bf16

    const int NB = (N + SCAN_BS - 1) / SCAN_BS;    // 98
    const int PB = (N + 63) / 64;                  // 1563

    hipMemsetAsync(counts, 0, (size_t)N * sizeof(int), stream);
    hipMemsetAsync(gmaxe, 0, 4 * sizeof(unsigned), stream);

    prep_kernel<<<1, 1024, 0, stream>>>(W_src, W_trg, a_trg, Wfrag, wcfrag);
    projhist_kernel<<<PB + HIST_BLOCKS, 256, 0, stream>>>(
        src, trg, Wfrag, wcfrag, a_src, ei, projb, s_src, s_trg, gmaxe, counts, N, E, PB);
    scan1_kernel<<<NB, SCAN_BS, 0, stream>>>(counts, cursor, bsum, N);
    scan2_kernel<<<1, 128, 0, stream>>>(bsum, NB, gmaxe, gmaxf);
    scan3_kernel<<<NB, SCAN_BS, 0, stream>>>(cursor, bsum, N);
    scatter_kernel<<<(E / 2 + 255) / 256, 256, 0, stream>>>(ei, cursor, perm_src, E);
    agg_kernel<<<(N + 3) / 4, 256, 0, stream>>>(cursor, counts, perm_src,
                                                s_src, s_trg, projb, gmaxf, out, N);
}